// Round 18
// baseline (128.021 us; speedup 1.0000x reference)
//
#include <hip/hip_runtime.h>
#include <hip/hip_bf16.h>
#include <math.h>
#include <stdint.h>

#define NROWS 1000000
#define NCOLS 100
#define NBINS 20
#define NB    19       // bin boundaries
#define W     50000u   // rows per bin
#define NH    2049     // buckets: 0 = catch-all (<0.5), 1..2048 = [0.5,1) in 2^-12 steps

// ---------- ws layout (dword offsets) ----------
#define HIST_DW   0u     // len 2052
#define BINS_DW   2052u  // len 80 dw = 40 doubles (byte 8208, 8-aligned)
#define TICKET_DW 2132u  // 1 dw (inside zero range)
#define ZERO_DW   2133u  // hist+bins+ticket zeroed inside k1
#define CONF_DW   2136u  // len 1000000 (byte 8544 = 534*16, 16B-aligned); sign bit = accuracy

// async DMA global->LDS, width 16B: lds dest = (wave-uniform base) + lane*16
#define GLOAD_LDS16(g, l) __builtin_amdgcn_global_load_lds(                    \
    (const __attribute__((address_space(1))) void*)(g),                        \
    (__attribute__((address_space(3))) void*)(l), 16, 0, 0)

__device__ __forceinline__ unsigned int bucket_of(unsigned int bits) {
    // bits = positive-f32 pattern. conf < 0.5 -> 0 (catch-all).
    if (bits < 0x3F000000u) return 0u;
    unsigned int t = (bits >> 12) - 258048u + 1u;   // 1..2048 for [0.5,1)
    return t > 2048u ? 2048u : t;
}

// ---------- K1: double-buffered DMA staging + counted vmcnt (frozen r17) ---
__global__ __launch_bounds__(256) void k1_rowmax(const float* __restrict__ x,
                                                 const int* __restrict__ labels,
                                                 float* __restrict__ conf,
                                                 unsigned int* __restrict__ zero_region) {
    __shared__ float4 ldsx4[3200];                 // two 1600-f4 buffers
    int tid = threadIdx.x;
    int gtid = blockIdx.x * 256 + tid;
    if (gtid < (int)ZERO_DW) zero_region[gtid] = 0u;   // hist + bins + ticket

    const int NTILES = NROWS / 64;  // 15625
    const float4* xb = reinterpret_cast<const float4*>(x);
    int lane = tid & 63;
    int w    = tid >> 6;
    int lab_next = 0, lab_cur = 0;

    float4* bufA = ldsx4;          // current (being reduced)
    float4* bufB = ldsx4 + 1600;   // being filled

#define K1_ISSUE(t, buf)                                                       \
    do {                                                                       \
        const float4* src_ = xb + (size_t)(t) * 1600;                          \
        _Pragma("unroll")                                                      \
        for (int i_ = 0; i_ < 6; i_++)                                         \
            GLOAD_LDS16(src_ + i_ * 256 + tid, (buf) + i_ * 256 + (tid & 192));\
        if (lane < 16)                                                         \
            GLOAD_LDS16(src_ + 1536 + 16 * w + lane, (buf) + 1536 + 16 * w);   \
        if ((tid & 3) == 0) lab_next = labels[(t) * 64 + (tid >> 2)];          \
    } while (0)

    int tile = blockIdx.x;
    if (tile < NTILES) K1_ISSUE(tile, bufA);

    while (tile < NTILES) {
        lab_cur = lab_next;
        int nxt = tile + gridDim.x;
        if (nxt < NTILES) {
            K1_ISSUE(nxt, bufB);
            asm volatile("s_waitcnt vmcnt(8)" ::: "memory");   // cur done; next in flight
        } else {
            asm volatile("s_waitcnt vmcnt(0)" ::: "memory");
        }
        __builtin_amdgcn_sched_barrier(0);
        __builtin_amdgcn_s_barrier();

        const float* rowp = (const float*)bufA + (tid >> 2) * 100 + (tid & 3) * 25;
        float best = rowp[0]; int bi = 0;
        #pragma unroll
        for (int k = 1; k < 25; k++) {
            float vv = rowp[k];
            if (vv > best) { best = vv; bi = k; }
        }
        bi += (tid & 3) * 25;
        #pragma unroll
        for (int mask = 1; mask <= 2; mask <<= 1) {
            float ov = __shfl_xor(best, mask);
            int   oi = __shfl_xor(bi,   mask);
            if (ov > best || (ov == best && oi < bi)) { best = ov; bi = oi; }
        }
        if ((tid & 3) == 0) {
            unsigned int bits = __float_as_uint(best);
            if (bi == lab_cur) bits |= 0x80000000u;
            conf[tile * 64 + (tid >> 2)] = __uint_as_float(bits);
        }
        __builtin_amdgcn_s_barrier();

        float4* tmp = bufA; bufA = bufB; bufB = tmp;
        tile = nxt;
    }
#undef K1_ISSUE
}

// ---------- K2: 2049-bucket histogram, 256x256 (2x more private hists) -----
__global__ __launch_bounds__(256) void k2_hist(const float* __restrict__ conf,
                                               unsigned int* __restrict__ hist) {
    __shared__ unsigned int lh[NH];
    for (int i = threadIdx.x; i < NH; i += 256) lh[i] = 0u;
    __syncthreads();
    const uint4* c4 = reinterpret_cast<const uint4*>(conf);
    int stride = gridDim.x * 256;
    for (int i = blockIdx.x * 256 + threadIdx.x; i < NROWS / 4; i += stride) {
        uint4 v = c4[i];
        atomicAdd(&lh[bucket_of(v.x & 0x7FFFFFFFu)], 1u);
        atomicAdd(&lh[bucket_of(v.y & 0x7FFFFFFFu)], 1u);
        atomicAdd(&lh[bucket_of(v.z & 0x7FFFFFFFu)], 1u);
        atomicAdd(&lh[bucket_of(v.w & 0x7FFFFFFFu)], 1u);
    }
    __syncthreads();
    for (int i = threadIdx.x; i < NH; i += 256) {
        unsigned int c = lh[i];
        if (c) atomicAdd(&hist[i], c);
    }
}

// ---------- K3: scan+bounds+split-accumulate + last-block finalize ---------
__global__ __launch_bounds__(256) void k3_accum(const float* __restrict__ conf,
                                                const unsigned int* __restrict__ hist,
                                                double* __restrict__ bins,
                                                unsigned int* __restrict__ ticket,
                                                float* __restrict__ out) {
    __shared__ unsigned int ptab[NH];   // prefix, later |= (slot+1)<<24 on boundary buckets
    __shared__ unsigned int s[256];
    __shared__ unsigned int bndS[NB];
    __shared__ float sFr[NB];
    __shared__ float sc[4][NBINS], sa[4][NBINS];
    __shared__ unsigned int amLast;
    int tid = threadIdx.x;

    // --- scan hist (2049) into ptab ---
    unsigned int loc[9];
    unsigned int tot = 0;
    int base = tid * 9;
    #pragma unroll
    for (int k = 0; k < 9; k++) {
        int idx = base + k;
        unsigned int v = (idx < NH) ? hist[idx] : 0u;
        loc[k] = tot; tot += v;
    }
    s[tid] = tot; __syncthreads();
    for (int off = 1; off < 256; off <<= 1) {
        unsigned int v = (tid >= off) ? s[tid - off] : 0u;
        __syncthreads();
        s[tid] += v;
        __syncthreads();
    }
    unsigned int excl = s[tid] - tot;
    #pragma unroll
    for (int k = 0; k < 9; k++) {
        int idx = base + k;
        if (idx < NH) ptab[idx] = excl + loc[k];
    }
    for (int i = tid; i < 4 * NBINS; i += 256) { (&sc[0][0])[i] = 0.f; (&sa[0][0])[i] = 0.f; }
    __syncthreads();

    // --- phase A: locate boundaries on the CLEAN prefix, save fr ---
    if (tid < NB) {
        unsigned int r = (unsigned int)(tid + 1) * W;
        int lo = 0, hi = NH - 1;
        while (lo < hi) {
            int mid = (lo + hi + 1) >> 1;
            if (ptab[mid] <= r) lo = mid; else hi = mid - 1;
        }
        unsigned int p = ptab[lo];
        if (p < r) {
            unsigned int cnt = ((lo + 1 < NH) ? ptab[lo + 1] : (unsigned int)NROWS) - p;
            bndS[tid] = (unsigned int)lo;
            sFr[tid]  = (float)(r - p) / (float)cnt;
        } else {
            bndS[tid] = 0xFFFFFFFFu;
        }
    }
    __syncthreads();
    // --- phase B: mark boundary buckets ---
    if (tid < NB && bndS[tid] != 0xFFFFFFFFu)
        ptab[bndS[tid]] |= (unsigned int)(tid + 1) << 24;
    __syncthreads();

    // --- main pass ---
    int wid = tid >> 6;
    const uint4* c4 = reinterpret_cast<const uint4*>(conf);
    int stride = gridDim.x * 256;
    for (int i = blockIdx.x * 256 + tid; i < NROWS / 4; i += stride) {
        uint4 q = c4[i];
        unsigned int bs[4] = { q.x, q.y, q.z, q.w };
        #pragma unroll
        for (int j = 0; j < 4; j++) {
            unsigned int raw = bs[j];
            float a = (float)(raw >> 31);
            unsigned int bits = raw & 0x7FFFFFFFu;
            float c = __uint_as_float(bits);
            unsigned int e = ptab[bucket_of(bits)];
            unsigned int t = e >> 24;
            if (t == 0u) {
                unsigned int bin = (e & 0xFFFFFFu) / W;
                atomicAdd(&sc[wid][bin], c); atomicAdd(&sa[wid][bin], a);
            } else {
                float fr = sFr[t - 1];
                atomicAdd(&sc[wid][t - 1], c * fr);
                atomicAdd(&sc[wid][t],     c * (1.f - fr));
                atomicAdd(&sa[wid][t - 1], a * fr);
                atomicAdd(&sa[wid][t],     a * (1.f - fr));
            }
        }
    }
    __syncthreads();
    if (tid < NBINS) {
        float tc = sc[0][tid] + sc[1][tid] + sc[2][tid] + sc[3][tid];
        float ta = sa[0][tid] + sa[1][tid] + sa[2][tid] + sa[3][tid];
        atomicAdd(&bins[tid],         (double)tc);
        atomicAdd(&bins[NBINS + tid], (double)ta);
    }
    // --- last-block finalize (replaces k4) ---
    // __syncthreads() drains vmcnt -> our bins atomics are at the coherence
    // point before the ticket increment. Last block reads bins ATOMICALLY
    // (coherent cross-XCD) and writes the output. No per-tile fences (r5
    // lesson) — this runs once per block at kernel end.
    __syncthreads();
    if (tid == 0) amLast = (atomicAdd(ticket, 1u) == gridDim.x - 1u) ? 1u : 0u;
    __syncthreads();
    if (amLast && tid == 0) {
        double ece = 0.0;
        for (int b = 0; b < NBINS; b++) {
            double avc = atomicAdd(&bins[b], 0.0)         / (double)W;
            double ava = atomicAdd(&bins[NBINS + b], 0.0) / (double)W;
            ece += fabs(avc - ava);
            out[1 + b] = (float)ava;
        }
        out[0] = (float)(ece * ((double)W / (double)NROWS));
    }
}

extern "C" void kernel_launch(void* const* d_in, const int* in_sizes, int n_in,
                              void* d_out, int out_size, void* d_ws, size_t ws_size,
                              hipStream_t stream) {
    const float* x      = (const float*)d_in[0];
    const int*   labels = (const int*)d_in[1];
    float*       out    = (float*)d_out;
    unsigned int* wd    = (unsigned int*)d_ws;

    unsigned int* hist   = wd + HIST_DW;
    double*       bins   = (double*)(wd + BINS_DW);
    unsigned int* ticket = wd + TICKET_DW;
    float*        conf   = (float*)(wd + CONF_DW);

    k1_rowmax<<<2048, 256, 0, stream>>>(x, labels, conf, wd);
    k2_hist  <<<256, 256, 0, stream>>>(conf, hist);
    k3_accum <<<512, 256, 0, stream>>>(conf, hist, bins, ticket, out);
}

// Round 19
// 115.039 us; speedup vs baseline: 1.1128x; 1.1128x over previous
//
#include <hip/hip_runtime.h>
#include <hip/hip_bf16.h>
#include <math.h>
#include <stdint.h>

#define NROWS 1000000
#define NCOLS 100
#define NBINS 20
#define NB    19       // bin boundaries
#define W     50000u   // rows per bin
#define NH    2049     // buckets: 0 = catch-all (<0.5), 1..2048 = [0.5,1) in 2^-12 steps

// ---------- ws layout (dword offsets) ----------
#define HIST_DW 0u       // len 2052
#define BINS_DW 2052u    // len 80 dw = 40 doubles (byte 8208, 8-aligned)
#define ZERO_DW 2132u    // hist+bins zeroed inside k1
#define CONF_DW 2136u    // len 1000000 (byte 8544 = 534*16, 16B-aligned); sign bit = accuracy

// async DMA global->LDS, width 16B: lds dest = (wave-uniform base) + lane*16
#define GLOAD_LDS16(g, l) __builtin_amdgcn_global_load_lds(                    \
    (const __attribute__((address_space(1))) void*)(g),                        \
    (__attribute__((address_space(3))) void*)(l), 16, 0, 0)

__device__ __forceinline__ unsigned int bucket_of(unsigned int bits) {
    // bits = positive-f32 pattern. conf < 0.5 -> 0 (catch-all).
    if (bits < 0x3F000000u) return 0u;
    unsigned int t = (bits >> 12) - 258048u + 1u;   // 1..2048 for [0.5,1)
    return t > 2048u ? 2048u : t;
}

// ---------- K1: double-buffered DMA staging + counted vmcnt (r17 frozen) ---
// Best measured configuration (115.6us total; k1 ~75us = 5.3 TB/s = 85% of
// the 6.3 TB/s device copy ceiling). r18's downstream consolidation
// regressed (-12us) and was reverted.
__global__ __launch_bounds__(256) void k1_rowmax(const float* __restrict__ x,
                                                 const int* __restrict__ labels,
                                                 float* __restrict__ conf,
                                                 unsigned int* __restrict__ zero_region) {
    __shared__ float4 ldsx4[3200];                 // two 1600-f4 buffers
    int tid = threadIdx.x;
    int gtid = blockIdx.x * 256 + tid;
    if (gtid < (int)ZERO_DW) zero_region[gtid] = 0u;   // hist + bins

    const int NTILES = NROWS / 64;  // 15625
    const float4* xb = reinterpret_cast<const float4*>(x);
    int lane = tid & 63;
    int w    = tid >> 6;
    int lab_next = 0, lab_cur = 0;

    float4* bufA = ldsx4;          // current (being reduced)
    float4* bufB = ldsx4 + 1600;   // being filled

#define K1_ISSUE(t, buf)                                                       \
    do {                                                                       \
        const float4* src_ = xb + (size_t)(t) * 1600;                          \
        _Pragma("unroll")                                                      \
        for (int i_ = 0; i_ < 6; i_++)                                         \
            GLOAD_LDS16(src_ + i_ * 256 + tid, (buf) + i_ * 256 + (tid & 192));\
        if (lane < 16)                                                         \
            GLOAD_LDS16(src_ + 1536 + 16 * w + lane, (buf) + 1536 + 16 * w);   \
        if ((tid & 3) == 0) lab_next = labels[(t) * 64 + (tid >> 2)];          \
    } while (0)

    int tile = blockIdx.x;
    if (tile < NTILES) K1_ISSUE(tile, bufA);

    while (tile < NTILES) {
        lab_cur = lab_next;
        int nxt = tile + gridDim.x;
        if (nxt < NTILES) {
            K1_ISSUE(nxt, bufB);
            asm volatile("s_waitcnt vmcnt(8)" ::: "memory");   // cur done; next in flight
        } else {
            asm volatile("s_waitcnt vmcnt(0)" ::: "memory");
        }
        __builtin_amdgcn_sched_barrier(0);
        __builtin_amdgcn_s_barrier();

        const float* rowp = (const float*)bufA + (tid >> 2) * 100 + (tid & 3) * 25;
        float best = rowp[0]; int bi = 0;
        #pragma unroll
        for (int k = 1; k < 25; k++) {
            float vv = rowp[k];
            if (vv > best) { best = vv; bi = k; }
        }
        bi += (tid & 3) * 25;
        #pragma unroll
        for (int mask = 1; mask <= 2; mask <<= 1) {
            float ov = __shfl_xor(best, mask);
            int   oi = __shfl_xor(bi,   mask);
            if (ov > best || (ov == best && oi < bi)) { best = ov; bi = oi; }
        }
        if ((tid & 3) == 0) {
            unsigned int bits = __float_as_uint(best);
            if (bi == lab_cur) bits |= 0x80000000u;
            conf[tile * 64 + (tid >> 2)] = __uint_as_float(bits);
        }
        __builtin_amdgcn_s_barrier();

        float4* tmp = bufA; bufA = bufB; bufB = tmp;
        tile = nxt;
    }
#undef K1_ISSUE
}

// ---------- K2: 2049-bucket histogram, per-block LDS (r17: 128x512) --------
__global__ __launch_bounds__(512) void k2_hist(const float* __restrict__ conf,
                                               unsigned int* __restrict__ hist) {
    __shared__ unsigned int lh[NH];
    for (int i = threadIdx.x; i < NH; i += 512) lh[i] = 0u;
    __syncthreads();
    const uint4* c4 = reinterpret_cast<const uint4*>(conf);
    int stride = gridDim.x * 512;
    for (int i = blockIdx.x * 512 + threadIdx.x; i < NROWS / 4; i += stride) {
        uint4 v = c4[i];
        atomicAdd(&lh[bucket_of(v.x & 0x7FFFFFFFu)], 1u);
        atomicAdd(&lh[bucket_of(v.y & 0x7FFFFFFFu)], 1u);
        atomicAdd(&lh[bucket_of(v.z & 0x7FFFFFFFu)], 1u);
        atomicAdd(&lh[bucket_of(v.w & 0x7FFFFFFFu)], 1u);
    }
    __syncthreads();
    for (int i = threadIdx.x; i < NH; i += 512) {
        unsigned int c = lh[i];
        if (c) atomicAdd(&hist[i], c);
    }
}

// ---------- K3: per-block redundant scan+bounds, then split-accumulate ----
__global__ __launch_bounds__(256) void k3_accum(const float* __restrict__ conf,
                                                const unsigned int* __restrict__ hist,
                                                double* __restrict__ bins) {
    __shared__ unsigned int ptab[NH];   // prefix, later |= (slot+1)<<24 on boundary buckets
    __shared__ unsigned int s[256];
    __shared__ unsigned int bndS[NB];
    __shared__ float sFr[NB];
    __shared__ float sc[4][NBINS], sa[4][NBINS];
    int tid = threadIdx.x;

    // --- scan hist (2049) into ptab ---
    unsigned int loc[9];
    unsigned int tot = 0;
    int base = tid * 9;
    #pragma unroll
    for (int k = 0; k < 9; k++) {
        int idx = base + k;
        unsigned int v = (idx < NH) ? hist[idx] : 0u;
        loc[k] = tot; tot += v;
    }
    s[tid] = tot; __syncthreads();
    for (int off = 1; off < 256; off <<= 1) {
        unsigned int v = (tid >= off) ? s[tid - off] : 0u;
        __syncthreads();
        s[tid] += v;
        __syncthreads();
    }
    unsigned int excl = s[tid] - tot;
    #pragma unroll
    for (int k = 0; k < 9; k++) {
        int idx = base + k;
        if (idx < NH) ptab[idx] = excl + loc[k];
    }
    for (int i = tid; i < 4 * NBINS; i += 256) { (&sc[0][0])[i] = 0.f; (&sa[0][0])[i] = 0.f; }
    __syncthreads();

    // --- phase A: locate boundaries on the CLEAN prefix, save fr ---
    if (tid < NB) {
        unsigned int r = (unsigned int)(tid + 1) * W;
        int lo = 0, hi = NH - 1;
        while (lo < hi) {
            int mid = (lo + hi + 1) >> 1;
            if (ptab[mid] <= r) lo = mid; else hi = mid - 1;
        }
        unsigned int p = ptab[lo];
        if (p < r) {
            unsigned int cnt = ((lo + 1 < NH) ? ptab[lo + 1] : (unsigned int)NROWS) - p;
            bndS[tid] = (unsigned int)lo;
            sFr[tid]  = (float)(r - p) / (float)cnt;
        } else {
            bndS[tid] = 0xFFFFFFFFu;
        }
    }
    __syncthreads();
    // --- phase B: mark boundary buckets ---
    if (tid < NB && bndS[tid] != 0xFFFFFFFFu)
        ptab[bndS[tid]] |= (unsigned int)(tid + 1) << 24;
    __syncthreads();

    // --- main pass ---
    int wid = tid >> 6;
    const uint4* c4 = reinterpret_cast<const uint4*>(conf);
    int stride = gridDim.x * 256;
    for (int i = blockIdx.x * 256 + tid; i < NROWS / 4; i += stride) {
        uint4 q = c4[i];
        unsigned int bs[4] = { q.x, q.y, q.z, q.w };
        #pragma unroll
        for (int j = 0; j < 4; j++) {
            unsigned int raw = bs[j];
            float a = (float)(raw >> 31);
            unsigned int bits = raw & 0x7FFFFFFFu;
            float c = __uint_as_float(bits);
            unsigned int e = ptab[bucket_of(bits)];
            unsigned int t = e >> 24;
            if (t == 0u) {
                unsigned int bin = (e & 0xFFFFFFu) / W;
                atomicAdd(&sc[wid][bin], c); atomicAdd(&sa[wid][bin], a);
            } else {
                float fr = sFr[t - 1];
                atomicAdd(&sc[wid][t - 1], c * fr);
                atomicAdd(&sc[wid][t],     c * (1.f - fr));
                atomicAdd(&sa[wid][t - 1], a * fr);
                atomicAdd(&sa[wid][t],     a * (1.f - fr));
            }
        }
    }
    __syncthreads();
    if (tid < NBINS) {
        float tc = sc[0][tid] + sc[1][tid] + sc[2][tid] + sc[3][tid];
        float ta = sa[0][tid] + sa[1][tid] + sa[2][tid] + sa[3][tid];
        atomicAdd(&bins[tid],         (double)tc);
        atomicAdd(&bins[NBINS + tid], (double)ta);
    }
}

// ---------- K4: finalize ----------
__global__ __launch_bounds__(64) void k4_final(const double* __restrict__ bins,
                                               float* __restrict__ out) {
    if (threadIdx.x == 0) {
        double ece = 0.0;
        for (int b = 0; b < NBINS; b++) {
            double avc = bins[b] / (double)W;
            double ava = bins[NBINS + b] / (double)W;
            ece += fabs(avc - ava);
            out[1 + b] = (float)ava;
        }
        out[0] = (float)(ece * ((double)W / (double)NROWS));
    }
}

extern "C" void kernel_launch(void* const* d_in, const int* in_sizes, int n_in,
                              void* d_out, int out_size, void* d_ws, size_t ws_size,
                              hipStream_t stream) {
    const float* x      = (const float*)d_in[0];
    const int*   labels = (const int*)d_in[1];
    float*       out    = (float*)d_out;
    unsigned int* wd    = (unsigned int*)d_ws;

    unsigned int* hist = wd + HIST_DW;
    double*       bins = (double*)(wd + BINS_DW);
    float*        conf = (float*)(wd + CONF_DW);

    k1_rowmax<<<2048, 256, 0, stream>>>(x, labels, conf, wd);
    k2_hist  <<<128, 512, 0, stream>>>(conf, hist);
    k3_accum <<<512, 256, 0, stream>>>(conf, hist, bins);
    k4_final <<<1, 64, 0, stream>>>(bins, out);
}